// Round 2
// baseline (266.989 us; speedup 1.0000x reference)
//
#include <hip/hip_runtime.h>
#include <hip/hip_bf16.h>

// Problem constants: features [B=32, D=1024, M=512] fp32.
#define B_ 32
#define D_ 1024
#define M_ 512
#define OUTROW 524800  // D*(D+1)/2
#define ALPHA_ 0.4f
#define EPS_ 1e-5f

typedef __bf16 bf16x8 __attribute__((ext_vector_type(8)));
typedef float f32x4 __attribute__((ext_vector_type(4)));

// ---------------------------------------------------------------------------
// Kernel A: cast features fp32->bf16 (same [b,d,m] layout) + diag[b,d] =
// sum_m f^2 / (2M)  (fp32 exact).
// One wave per row (512 elems), 4 rows per 256-thread block.
// ---------------------------------------------------------------------------
__global__ __launch_bounds__(256) void prep_kernel(
    const float* __restrict__ feat, __bf16* __restrict__ featbf,
    float* __restrict__ diag)
{
    const int w = threadIdx.x >> 6, l = threadIdx.x & 63;
    const int row = blockIdx.x * 4 + w;          // 0 .. 32767
    const float4* fp = (const float4*)(feat + (size_t)row * M_);
    float4 v0 = fp[l * 2];
    float4 v1 = fp[l * 2 + 1];
    bf16x8 h;
    h[0] = (__bf16)v0.x; h[1] = (__bf16)v0.y; h[2] = (__bf16)v0.z; h[3] = (__bf16)v0.w;
    h[4] = (__bf16)v1.x; h[5] = (__bf16)v1.y; h[6] = (__bf16)v1.z; h[7] = (__bf16)v1.w;
    *(bf16x8*)(featbf + (size_t)row * M_ + l * 8) = h;
    float s = v0.x*v0.x + v0.y*v0.y + v0.z*v0.z + v0.w*v0.w
            + v1.x*v1.x + v1.y*v1.y + v1.z*v1.z + v1.w*v1.w;
    #pragma unroll
    for (int off = 32; off; off >>= 1) s += __shfl_down(s, off);
    if (l == 0) diag[row] = s * (1.0f / (2.0f * M_));
}

// ---------------------------------------------------------------------------
// Kernel B: upper-triangular-tile Gram GEMM (bf16 MFMA 16x16x32), fused
// dcov -> pow epilogue. Writes uncentered p to packed triuvec slots of d_out,
// accumulates row sums (by symmetry row==col means) and per-batch total.
// Tile 128x128, BK=64, 4 waves (each 64x64 via 4x4 frags).
// LDS staged via global_load_lds width=16 with XOR chunk swizzle
// (chunk position = c ^ (row&7)) to spread the 128B row stride over banks.
// ---------------------------------------------------------------------------
__global__ __launch_bounds__(256, 1) void gram_kernel(
    const __bf16* __restrict__ feat, const float* __restrict__ diag,
    float* __restrict__ out, float* __restrict__ rowsum,
    float* __restrict__ totals)
{
    __shared__ __bf16 As[128 * 64];
    __shared__ __bf16 Bs[128 * 64];

    const int t = threadIdx.x;
    const int w = t >> 6, l = t & 63;
    const int quad = l >> 4, l15 = l & 15;
    const int b = blockIdx.y;

    // decode upper tile pair (ti <= tj) from linear index in [0,36)
    int u = blockIdx.x, ti = 0;
    while (u >= 8 - ti) { u -= 8 - ti; ti++; }
    const int tj = ti + u;
    const bool diagTile = (ti == tj);

    const __bf16* Ab = feat + (size_t)b * (D_ * M_) + (size_t)ti * 128 * M_;
    const __bf16* Bb = feat + (size_t)b * (D_ * M_) + (size_t)tj * 128 * M_;

    const int wm = w >> 1, wn = w & 1;

    f32x4 acc[4][4] = {};

    for (int k0 = 0; k0 < M_; k0 += 64) {
        #pragma unroll
        for (int it = 0; it < 4; ++it) {
            const int idx = it * 256 + t;        // chunk index 0..1023
            const int row = idx >> 3;            // 0..127
            const int cg = (idx & 7) ^ (row & 7);  // swizzled global chunk
            const __bf16* ga = Ab + row * M_ + k0 + cg * 8;
            const __bf16* gb = Bb + row * M_ + k0 + cg * 8;
            // wave-uniform LDS base; HW adds lane*16B
            __builtin_amdgcn_global_load_lds(
                (const __attribute__((address_space(1))) void*)ga,
                (__attribute__((address_space(3))) void*)(As + (it * 256 + w * 64) * 8),
                16, 0, 0);
            __builtin_amdgcn_global_load_lds(
                (const __attribute__((address_space(1))) void*)gb,
                (__attribute__((address_space(3))) void*)(Bs + (it * 256 + w * 64) * 8),
                16, 0, 0);
        }
        __syncthreads();

        #pragma unroll
        for (int kk = 0; kk < 64; kk += 32) {
            bf16x8 af[4], bfr[4];
            #pragma unroll
            for (int mi = 0; mi < 4; ++mi) {
                const int row = wm * 64 + mi * 16 + l15;
                const int sc = ((kk >> 3) + quad) ^ (row & 7);
                af[mi] = *(const bf16x8*)(As + row * 64 + sc * 8);
            }
            #pragma unroll
            for (int nj = 0; nj < 4; ++nj) {
                const int row = wn * 64 + nj * 16 + l15;
                const int sc = ((kk >> 3) + quad) ^ (row & 7);
                bfr[nj] = *(const bf16x8*)(Bs + row * 64 + sc * 8);
            }
            #pragma unroll
            for (int mi = 0; mi < 4; ++mi)
                #pragma unroll
                for (int nj = 0; nj < 4; ++nj)
                    acc[mi][nj] = __builtin_amdgcn_mfma_f32_16x16x32_bf16(
                        af[mi], bfr[nj], acc[mi][nj], 0, 0, 0);
        }
        __syncthreads();
    }

    // ---------------- epilogue ----------------
    const int gi0 = ti * 128 + wm * 64;
    const int gj0 = tj * 128 + wn * 64;
    const float* diagB = diag + b * D_;

    float di[4][4], dj[4];
    #pragma unroll
    for (int mi = 0; mi < 4; ++mi)
        #pragma unroll
        for (int r = 0; r < 4; ++r)
            di[mi][r] = diagB[gi0 + mi * 16 + quad * 4 + r];
    #pragma unroll
    for (int nj = 0; nj < 4; ++nj)
        dj[nj] = diagB[gj0 + nj * 16 + l15];

    float* outB = out + (size_t)b * OUTROW;
    float rs[4][4] = {};
    float cs[4] = {};
    float wt = 0.f;
    const float invK = 1.0f / 512.0f;  // dcov = di + dj - dot/512

    #pragma unroll
    for (int mi = 0; mi < 4; ++mi) {
        #pragma unroll
        for (int nj = 0; nj < 4; ++nj) {
            const f32x4 a = acc[mi][nj];
            const int j = gj0 + nj * 16 + l15;
            #pragma unroll
            for (int r = 0; r < 4; ++r) {
                const int i = gi0 + mi * 16 + quad * 4 + r;
                float d = di[mi][r] + dj[nj] - a[r] * invK;
                if (i == j) d = 0.0f;   // exact: ref has dcov(i,i) == 0
                d = fmaxf(d, 0.0f);
                const float p = __builtin_exp2f(ALPHA_ * __builtin_log2f(d + EPS_));
                rs[mi][r] += p;
                cs[nj] += p;
                wt += p;
                if (!diagTile || j >= i)
                    outB[(size_t)i * D_ - ((size_t)i * (i + 1)) / 2 + j] = p;
            }
        }
    }

    // row-sum contributions (rows of this tile): reduce across l15 lanes
    #pragma unroll
    for (int mi = 0; mi < 4; ++mi) {
        #pragma unroll
        for (int r = 0; r < 4; ++r) {
            float v = rs[mi][r];
            v += __shfl_xor(v, 1); v += __shfl_xor(v, 2);
            v += __shfl_xor(v, 4); v += __shfl_xor(v, 8);
            if (l15 == 0)
                unsafeAtomicAdd(&rowsum[b * D_ + gi0 + mi * 16 + quad * 4 + r], v);
        }
    }
    // col-sum contributions map to rowsum[j] by symmetry (off-diag tiles only)
    if (!diagTile) {
        #pragma unroll
        for (int nj = 0; nj < 4; ++nj) {
            float v = cs[nj];
            v += __shfl_xor(v, 16); v += __shfl_xor(v, 32);
            if (quad == 0)
                unsafeAtomicAdd(&rowsum[b * D_ + gj0 + nj * 16 + l15], v);
        }
    }
    // batch total (off-diag tiles counted twice: tile + mirror)
    float v = wt;
    #pragma unroll
    for (int off = 32; off; off >>= 1) v += __shfl_down(v, off);
    if (l == 0) unsafeAtomicAdd(&totals[b], diagTile ? v : 2.0f * v);
}

// ---------------------------------------------------------------------------
// Kernel C: in-place double-centering on packed output.
// out[b, tri(i,j)] -= rm[i] + rm[j] - tm
// ---------------------------------------------------------------------------
__global__ __launch_bounds__(256) void center_kernel(
    float* __restrict__ out, const float* __restrict__ rowsum,
    const float* __restrict__ totals)
{
    const int i = blockIdx.y, b = blockIdx.z;
    const int pos = blockIdx.x * 256 + threadIdx.x;
    const int L = D_ - i;
    if (pos >= L) return;
    const int j = i + pos;
    const float* rsB = rowsum + b * D_;
    const float rmi = rsB[i] * (1.0f / D_);
    const float rmj = rsB[j] * (1.0f / D_);
    const float tm = totals[b] * (1.0f / ((float)D_ * (float)D_));
    const size_t k = (size_t)b * OUTROW + (size_t)i * D_ - ((size_t)i * (i + 1)) / 2 + j;
    out[k] = out[k] - rmi - rmj + tm;
}

// ---------------------------------------------------------------------------
extern "C" void kernel_launch(void* const* d_in, const int* in_sizes, int n_in,
                              void* d_out, int out_size, void* d_ws, size_t ws_size,
                              hipStream_t stream) {
    const float* feat = (const float*)d_in[0];
    float* out = (float*)d_out;

    char* ws = (char*)d_ws;
    __bf16* featbf = (__bf16*)ws;                            // 33,554,432 B
    float* diag    = (float*)(ws + 33554432);                //    131,072 B
    float* rowsum  = (float*)(ws + 33554432 + 131072);       //    131,072 B
    float* totals  = (float*)(ws + 33554432 + 262144);       //        128 B

    // zero rowsum + totals (ws is re-poisoned 0xAA before every launch)
    (void)hipMemsetAsync(rowsum, 0, 131072 + 128, stream);

    prep_kernel<<<dim3((B_ * D_) / 4), dim3(256), 0, stream>>>(feat, featbf, diag);
    gram_kernel<<<dim3(36, B_), dim3(256), 0, stream>>>(featbf, diag, out, rowsum, totals);
    center_kernel<<<dim3(4, D_, B_), dim3(256), 0, stream>>>(out, rowsum, totals);
}

// Round 3
// 206.918 us; speedup vs baseline: 1.2903x; 1.2903x over previous
//
#include <hip/hip_runtime.h>
#include <hip/hip_bf16.h>

// Problem constants: features [B=32, D=1024, M=512] fp32.
#define B_ 32
#define D_ 1024
#define M_ 512
#define OUTROW 524800  // D*(D+1)/2
#define ALPHA_ 0.4f
#define EPS_ 1e-5f

typedef __bf16 bf16x8 __attribute__((ext_vector_type(8)));
typedef float f32x4 __attribute__((ext_vector_type(4)));

// ---------------------------------------------------------------------------
// Kernel A: cast features fp32->bf16 + diag[b,d] = sum_m f^2 / (2M) (fp32).
// One wave per row (512 elems), 4 rows per 256-thread block.
// ---------------------------------------------------------------------------
__global__ __launch_bounds__(256) void prep_kernel(
    const float* __restrict__ feat, __bf16* __restrict__ featbf,
    float* __restrict__ diag)
{
    const int w = threadIdx.x >> 6, l = threadIdx.x & 63;
    const int row = blockIdx.x * 4 + w;          // 0 .. 32767
    const float4* fp = (const float4*)(feat + (size_t)row * M_);
    float4 v0 = fp[l * 2];
    float4 v1 = fp[l * 2 + 1];
    bf16x8 h;
    h[0] = (__bf16)v0.x; h[1] = (__bf16)v0.y; h[2] = (__bf16)v0.z; h[3] = (__bf16)v0.w;
    h[4] = (__bf16)v1.x; h[5] = (__bf16)v1.y; h[6] = (__bf16)v1.z; h[7] = (__bf16)v1.w;
    *(bf16x8*)(featbf + (size_t)row * M_ + l * 8) = h;
    float s = v0.x*v0.x + v0.y*v0.y + v0.z*v0.z + v0.w*v0.w
            + v1.x*v1.x + v1.y*v1.y + v1.z*v1.z + v1.w*v1.w;
    #pragma unroll
    for (int off = 32; off; off >>= 1) s += __shfl_down(s, off);
    if (l == 0) diag[row] = s * (1.0f / (2.0f * M_));
}

// ---------------------------------------------------------------------------
// Kernel B: upper-triangular-tile Gram GEMM (bf16 MFMA 16x16x32), fused
// dcov -> pow epilogue, XCD-batch-swizzled so each XCD's 1MB/batch panel set
// stays L2-resident. BK=32 double-buffered (2 x 16 KB LDS), one barrier per
// k-step. Tile 128x128, 4 waves (64x64 each via 4x4 frags).
// ---------------------------------------------------------------------------
__global__ __launch_bounds__(256, 3) void gram_kernel(
    const __bf16* __restrict__ feat, const float* __restrict__ diag,
    float* __restrict__ out, float* __restrict__ rowsum,
    float* __restrict__ totals)
{
    // [stage][slot] ; slot = row*4 + swizzled-chunk, 16B per slot
    __shared__ __bf16 As[2][512 * 8];
    __shared__ __bf16 Bs[2][512 * 8];

    const int t = threadIdx.x;
    const int w = t >> 6, l = t & 63;
    const int quad = l >> 4, l15 = l & 15;

    // XCD-aware decode: linear id -> (xcd, slot); each XCD owns batches
    // {xcd, xcd+8, xcd+16, xcd+24} processed sequentially -> per-XCD L2 reuse.
    const int L = blockIdx.x;
    const int xcd = L & 7;
    const int slot = L >> 3;                 // 0..143
    const int b = xcd + 8 * (slot / 36);
    int u = slot % 36, ti = 0;
    while (u >= 8 - ti) { u -= 8 - ti; ti++; }
    const int tj = ti + u;
    const bool diagTile = (ti == tj);

    const __bf16* Ab = feat + (size_t)b * (D_ * M_) + (size_t)ti * 128 * M_;
    const __bf16* Bb = feat + (size_t)b * (D_ * M_) + (size_t)tj * 128 * M_;

    const int wm = w >> 1, wn = w & 1;

    f32x4 acc[4][4] = {};

    // stage s: load A/B rows [0,128) cols [s*32, s*32+32) into buffer s&1
    auto stage = [&](int s) {
        const int koff = s * 32;
        const int sb = s & 1;
        #pragma unroll
        for (int it = 0; it < 2; ++it) {
            const int idx = it * 256 + t;        // slot 0..511
            const int row = idx >> 2;            // 0..127
            const int cg = (idx & 3) ^ (row & 3);  // swizzled chunk-of-8
            const __bf16* ga = Ab + row * M_ + koff + cg * 8;
            const __bf16* gb = Bb + row * M_ + koff + cg * 8;
            __builtin_amdgcn_global_load_lds(
                (const __attribute__((address_space(1))) void*)ga,
                (__attribute__((address_space(3))) void*)(&As[sb][(it * 256 + w * 64) * 8]),
                16, 0, 0);
            __builtin_amdgcn_global_load_lds(
                (const __attribute__((address_space(1))) void*)gb,
                (__attribute__((address_space(3))) void*)(&Bs[sb][(it * 256 + w * 64) * 8]),
                16, 0, 0);
        }
    };

    stage(0);
    for (int k0 = 0; k0 < 16; ++k0) {
        __syncthreads();                 // buffer k0&1 ready (barrier drains vmcnt)
        if (k0 + 1 < 16) stage(k0 + 1);  // prefetch into other buffer

        const int sb = k0 & 1;
        bf16x8 af[4], bfr[4];
        #pragma unroll
        for (int mi = 0; mi < 4; ++mi) {
            const int row = wm * 64 + mi * 16 + l15;
            af[mi] = *(const bf16x8*)(&As[sb][(row * 4 + (quad ^ (row & 3))) * 8]);
        }
        #pragma unroll
        for (int nj = 0; nj < 4; ++nj) {
            const int row = wn * 64 + nj * 16 + l15;
            bfr[nj] = *(const bf16x8*)(&Bs[sb][(row * 4 + (quad ^ (row & 3))) * 8]);
        }
        #pragma unroll
        for (int mi = 0; mi < 4; ++mi)
            #pragma unroll
            for (int nj = 0; nj < 4; ++nj)
                acc[mi][nj] = __builtin_amdgcn_mfma_f32_16x16x32_bf16(
                    af[mi], bfr[nj], acc[mi][nj], 0, 0, 0);
    }

    // ---------------- epilogue ----------------
    const int gi0 = ti * 128 + wm * 64;
    const int gj0 = tj * 128 + wn * 64;
    const float* diagB = diag + b * D_;

    float di[4][4], dj[4];
    #pragma unroll
    for (int mi = 0; mi < 4; ++mi)
        #pragma unroll
        for (int r = 0; r < 4; ++r)
            di[mi][r] = diagB[gi0 + mi * 16 + quad * 4 + r];
    #pragma unroll
    for (int nj = 0; nj < 4; ++nj)
        dj[nj] = diagB[gj0 + nj * 16 + l15];

    float* outB = out + (size_t)b * OUTROW;
    float rs[4][4] = {};
    float cs[4] = {};
    float wt = 0.f;
    const float invK = 1.0f / 512.0f;  // dcov = di + dj - dot/512

    #pragma unroll
    for (int mi = 0; mi < 4; ++mi) {
        #pragma unroll
        for (int nj = 0; nj < 4; ++nj) {
            const f32x4 a = acc[mi][nj];
            const int j = gj0 + nj * 16 + l15;
            #pragma unroll
            for (int r = 0; r < 4; ++r) {
                const int i = gi0 + mi * 16 + quad * 4 + r;
                float d = di[mi][r] + dj[nj] - a[r] * invK;
                if (i == j) d = 0.0f;   // exact: ref has dcov(i,i) == 0
                d = fmaxf(d, 0.0f);
                const float p = __builtin_exp2f(ALPHA_ * __builtin_log2f(d + EPS_));
                rs[mi][r] += p;
                cs[nj] += p;
                wt += p;
                if (!diagTile || j >= i)
                    outB[(size_t)i * D_ - ((size_t)i * (i + 1)) / 2 + j] = p;
            }
        }
    }

    // row-sum contributions: reduce across l15 lanes
    #pragma unroll
    for (int mi = 0; mi < 4; ++mi) {
        #pragma unroll
        for (int r = 0; r < 4; ++r) {
            float v = rs[mi][r];
            v += __shfl_xor(v, 1); v += __shfl_xor(v, 2);
            v += __shfl_xor(v, 4); v += __shfl_xor(v, 8);
            if (l15 == 0)
                unsafeAtomicAdd(&rowsum[b * D_ + gi0 + mi * 16 + quad * 4 + r], v);
        }
    }
    // col-sum contributions map to rowsum[j] by symmetry (off-diag tiles only)
    if (!diagTile) {
        #pragma unroll
        for (int nj = 0; nj < 4; ++nj) {
            float v = cs[nj];
            v += __shfl_xor(v, 16); v += __shfl_xor(v, 32);
            if (quad == 0)
                unsafeAtomicAdd(&rowsum[b * D_ + gj0 + nj * 16 + l15], v);
        }
    }
    // batch total (off-diag tiles counted twice: tile + mirror)
    float v = wt;
    #pragma unroll
    for (int off = 32; off; off >>= 1) v += __shfl_down(v, off);
    if (l == 0) unsafeAtomicAdd(&totals[b], diagTile ? v : 2.0f * v);
}

// ---------------------------------------------------------------------------
// Kernel C: in-place double-centering. One block per (row i, batch b);
// threads stride the packed row. out[b,tri(i,j)] -= rm[i]+rm[j]-tm
// ---------------------------------------------------------------------------
__global__ __launch_bounds__(256) void center_kernel(
    float* __restrict__ out, const float* __restrict__ rowsum,
    const float* __restrict__ totals)
{
    const int i = blockIdx.x, b = blockIdx.y;
    const float* rsB = rowsum + b * D_;
    const float rmi = rsB[i] * (1.0f / D_);
    const float tm = totals[b] * (1.0f / ((float)D_ * (float)D_));
    float* row = out + (size_t)b * OUTROW + (size_t)i * D_ - ((size_t)i * (i + 1)) / 2;
    for (int j = i + threadIdx.x; j < D_; j += 256) {
        row[j] = row[j] - rmi - rsB[j] * (1.0f / D_) + tm;
    }
}

// ---------------------------------------------------------------------------
extern "C" void kernel_launch(void* const* d_in, const int* in_sizes, int n_in,
                              void* d_out, int out_size, void* d_ws, size_t ws_size,
                              hipStream_t stream) {
    const float* feat = (const float*)d_in[0];
    float* out = (float*)d_out;

    char* ws = (char*)d_ws;
    __bf16* featbf = (__bf16*)ws;                            // 33,554,432 B
    float* diag    = (float*)(ws + 33554432);                //    131,072 B
    float* rowsum  = (float*)(ws + 33554432 + 131072);       //    131,072 B
    float* totals  = (float*)(ws + 33554432 + 262144);       //        128 B

    // zero rowsum + totals (ws is re-poisoned 0xAA before every launch)
    (void)hipMemsetAsync(rowsum, 0, 131072 + 128, stream);

    prep_kernel<<<dim3((B_ * D_) / 4), dim3(256), 0, stream>>>(feat, featbf, diag);
    gram_kernel<<<dim3(36 * B_), dim3(256), 0, stream>>>(featbf, diag, out, rowsum, totals);
    center_kernel<<<dim3(D_, B_), dim3(256), 0, stream>>>(out, rowsum, totals);
}